// Round 10
// baseline (1683.618 us; speedup 1.0000x reference)
//
#include <hip/hip_runtime.h>
#include <hip/hip_bf16.h>
#include <stdint.h>

#define T_STEPS 512
#define BATCH   256
#define DIN     85
#define HDIM    512
#define NOUT    33

#define BBLK  16     // batch rows per group
#define HS    32     // H columns per wave-member slice
#define LDA   1040   // bytes per padded row of h A-tile (520 elems, 16B-aligned)
#define LDX   208    // bytes per padded row of x A-tile (104 elems)

// bf16 NaN|NaN pair — unreachable as packed h output (|h|<1, finite),
// used as the "not yet written" sentinel so the data is its own flag.
#define SENT  0x7FC07FC0u

typedef __attribute__((ext_vector_type(8))) short s8v;       // 8 x bf16
typedef __attribute__((ext_vector_type(4))) float f4v;       // MFMA accumulator
typedef __attribute__((ext_vector_type(4))) uint32_t u32x4;  // 16B chunk

__device__ __forceinline__ uint16_t f2bf(float f) {
    uint32_t x = __builtin_bit_cast(uint32_t, f);
    uint32_t r = (x + 0x7fffu + ((x >> 16) & 1u)) >> 16;
    return (uint16_t)r;
}
__device__ __forceinline__ float sigm(float v) {
    v = fminf(fmaxf(v, -30.f), 30.f);
    return 1.f / (1.f + __expf(-v));
}
__device__ __forceinline__ float tanh_f(float v) {
    v = fminf(fmaxf(v, -15.f), 15.f);
    float e = __expf(2.f * v);
    return (e - 1.f) / (e + 1.f);
}
__device__ __forceinline__ s8v cvt8(const float* p) {
    s8v v;
#pragma unroll
    for (int j = 0; j < 8; ++j) v[j] = (short)f2bf(p[j]);
    return v;
}

// r16 = r15 with the spill fixed. r15's regression was a confound:
// __launch_bounds__(512,1) made the compiler cap VGPRs at 128 (< the 152
// VGPRs of weight fragments alone) -> weights spilled to scratch -> +87MB
// fetch / +41MB write of scratch traffic per dispatch. (512,2) declares the
// true occupancy (8-wave block, 2 waves/EU) -> cap 256, demand ~215, no
// spill. This is the clean test of the volume-halving fusion:
// intra-block exchange via LDS, each block polls only 7/8 of the tile.
__device__ __forceinline__ void issue4_dev(u32x4& v, const uint32_t* p) {
    asm volatile("global_load_dwordx4 %0, %1, off sc0 sc1"
                 : "+v"(v) : "v"(p) : "memory");
}
__device__ __forceinline__ void wait_vm1(u32x4& a, u32x4& b) {
    // in-order retirement (m135): <=1 outstanding means the 2 older poll
    // loads are done while the younger fire-and-forget h-store may still be
    // in flight — we never pay for the store ack.
    asm volatile("s_waitcnt vmcnt(1)"
                 : "+v"(a), "+v"(b) :: "memory");
}
__device__ __forceinline__ void wait_vm0(u32x4& a, u32x4& b) {
    asm volatile("s_waitcnt vmcnt(0)"
                 : "+v"(a), "+v"(b) :: "memory");
}
__device__ __forceinline__ uint32_t has_sent(const u32x4& v) {
    return (uint32_t)(v[0] == SENT) | (uint32_t)(v[1] == SENT) |
           (uint32_t)(v[2] == SENT) | (uint32_t)(v[3] == SENT);
}

// Fill hbuf with the sentinel before the recurrence.
__global__ __launch_bounds__(256) void lstm_init(uint32_t* __restrict__ hbuf)
{
    const size_t n4 = (size_t)(T_STEPS + 1) * BATCH * HDIM / 2 / 4;
    u32x4 s; s[0] = SENT; s[1] = SENT; s[2] = SENT; s[3] = SENT;
    u32x4* p = (u32x4*)hbuf;
    for (size_t i = (size_t)blockIdx.x * 256 + threadIdx.x; i < n4;
         i += (size_t)gridDim.x * 256)
        p[i] = s;
}

// Persistent recurrence kernel. 128 blocks x 512 threads = 16 groups x 8
// blocks; each block hosts 2 members (64 H-cols), 8 waves = 2 members x 4
// gates. Group owns 16 batch rows. Weights live in registers per wave.
// Post-barrier order (r13-proven): poll issue -> pointwise -> h-store ->
// own-col LDS -> store_x -> wait_vm1 -> reissue rounds -> hA writes -> barrier.
__global__ __launch_bounds__(512, 2) void lstm_rec(
    const float* __restrict__ x,
    const float* __restrict__ Wxi, const float* __restrict__ Wxf,
    const float* __restrict__ Wxo, const float* __restrict__ Wxc,
    const float* __restrict__ Whi, const float* __restrict__ bhi,
    const float* __restrict__ Whf, const float* __restrict__ bhf,
    const float* __restrict__ Who, const float* __restrict__ bho,
    const float* __restrict__ Whc, const float* __restrict__ bhc,
    uint16_t* __restrict__ hbuf)      // [T_STEPS+1][BATCH][HDIM] bf16 (scratch)
{
    __shared__ __align__(16) uint8_t hA[16 * LDA];   // 16.6 KB
    __shared__ __align__(16) uint8_t xA[16 * LDX];   // 3.3 KB
    __shared__ float gbuf[2][4 * 16 * 33];           // 16.9 KB

    const int tid  = threadIdx.x;
    const int bid  = blockIdx.x;
    const int xcd  = bid & 7;
    const int slot = bid >> 3;            // 0..15
    const int grp  = xcd * 2 + (slot >> 3);
    const int blkm = slot & 7;            // block index within group, 0..7
    const int b0   = grp * BBLK;
    const int bslice = blkm * 64;         // block's 64 own columns

    const int wave  = tid >> 6;           // 0..7
    const int memb  = wave >> 2;          // member within block: 0..1
    const int gate  = wave & 3;           // 0=i 1=f 2=o 3=c
    const int lane  = tid & 63;
    const int col16 = lane & 15;
    const int quad  = lane >> 4;
    const int hs    = bslice + memb * HS; // this wave's 32 columns

    const float* Wh  = (gate == 0) ? Whi : (gate == 1) ? Whf : (gate == 2) ? Who : Whc;
    const float* Wxp = (gate == 0) ? Wxi : (gate == 1) ? Wxf : (gate == 2) ? Wxo : Wxc;

    // ---- B-fragments (weights) into registers, once (fp32 -> bf16 RNE) ----
    s8v bh[2][16];
#pragma unroll
    for (int nt = 0; nt < 2; ++nt) {
        const float* rowp = Wh + (size_t)(hs + nt * 16 + col16) * HDIM;
#pragma unroll
        for (int kt = 0; kt < 16; ++kt)
            bh[nt][kt] = cvt8(rowp + kt * 32 + quad * 8);
    }
    s8v bx[2][3];
#pragma unroll
    for (int nt = 0; nt < 2; ++nt) {
        const float* rowp = Wxp + (size_t)(hs + nt * 16 + col16) * DIN;
#pragma unroll
        for (int kt = 0; kt < 3; ++kt) {
            s8v v;
#pragma unroll
            for (int j = 0; j < 8; ++j) {
                int k = kt * 32 + quad * 8 + j;
                v[j] = (k < DIN) ? (short)f2bf(rowp[k]) : (short)0;
            }
            bx[nt][kt] = v;
        }
    }

    // ---- pointwise mapping: thread -> (member pm, row r, cols gcol,gcol+1) ----
    const int pm   = tid >> 8;                 // member whose slice we finish
    const int t256 = tid & 255;
    const int r    = t256 >> 4;
    const int c0l  = (t256 & 15) * 2;          // col within member's 32
    const int gcol = bslice + pm * HS + c0l;   // global H column
    const float bi0 = bhi[gcol], bi1 = bhi[gcol + 1];
    const float bf0 = bhf[gcol], bf1 = bhf[gcol + 1];
    const float bo0 = bho[gcol], bo1 = bho[gcol + 1];
    const float bc0 = bhc[gcol], bc1 = bhc[gcol + 1];
    float C0 = 0.f, C1 = 0.f;

    uint32_t* hbuf32 = (uint32_t*)hbuf;
    const size_t hslot = ((size_t)(b0 + r) * HDIM + gcol) >> 1;

    // ---- poll chunk mapping: 1024 chunks (16 rows x 64 16B-cols), 2/thread
    const int prow0 = tid >> 6;          // rows 0..7
    const int prow1 = prow0 + 8;         // rows 8..15
    const int rc8   = tid & 63;          // 16B column
    // block's own 64 cols = 8 chunk-cols [blkm*8, blkm*8+8): arrive via LDS
    const uint32_t ownm = ((uint32_t)(rc8 >> 3) == (uint32_t)blkm) ? 1u : 0u;

    // ---- x prefetch (fp32 registers): 1536 slots = 512 threads x 3 ----
    float xreg[3];
    auto load_x = [&](int t) {
#pragma unroll
        for (int j = 0; j < 3; ++j) {
            int v = tid + j * 512;
            int row = v / 96, k = v % 96;
            xreg[j] = (k < DIN) ? x[(size_t)(t * BATCH + b0 + row) * DIN + k] : 0.f;
        }
    };
    auto store_x = [&]() {
#pragma unroll
        for (int j = 0; j < 3; ++j) {
            int v = tid + j * 512;
            int row = v / 96, k = v % 96;
            *(uint16_t*)(xA + row * LDX + k * 2) = f2bf(xreg[j]);
        }
    };

    // init: h(0)=0 in LDS, stage x(0)
    load_x(0);
    for (int j = tid; j < 16 * LDA / 16; j += 512) {
        s8v z;
#pragma unroll
        for (int q = 0; q < 8; ++q) z[q] = 0;
        ((s8v*)hA)[j] = z;
    }
    store_x();
    __syncthreads();

    u32x4 v0 = {SENT, SENT, SENT, SENT};
    u32x4 v1 = v0;

    for (int t = 0; t < T_STEPS; ++t) {
        const int last = (t == T_STEPS - 1);

        // x(t+1) loads fly under the GEMM
        if (!last) load_x(t + 1);

        // ---- GEMM: this wave's gate, 16 rows x 32 cols (identical to r13) ----
        f4v acc0 = {0.f, 0.f, 0.f, 0.f}, acc1 = {0.f, 0.f, 0.f, 0.f};
#pragma unroll
        for (int kt = 0; kt < 16; ++kt) {
            s8v a = *(const s8v*)(hA + col16 * LDA + kt * 64 + quad * 16);
            acc0 = __builtin_amdgcn_mfma_f32_16x16x32_bf16(a, bh[0][kt], acc0, 0, 0, 0);
            acc1 = __builtin_amdgcn_mfma_f32_16x16x32_bf16(a, bh[1][kt], acc1, 0, 0, 0);
        }
#pragma unroll
        for (int kt = 0; kt < 3; ++kt) {
            s8v a = *(const s8v*)(xA + col16 * LDX + kt * 64 + quad * 16);
            acc0 = __builtin_amdgcn_mfma_f32_16x16x32_bf16(a, bx[0][kt], acc0, 0, 0, 0);
            acc1 = __builtin_amdgcn_mfma_f32_16x16x32_bf16(a, bx[1][kt], acc1, 0, 0, 0);
        }
        // Raw pre-activations to the member's gbuf. C/D: col=lane&15, row=quad*4+rr
#pragma unroll
        for (int rr = 0; rr < 4; ++rr) {
            int b = quad * 4 + rr;
            gbuf[memb][(gate * 16 + b) * 33 + col16]      = acc0[rr];
            gbuf[memb][(gate * 16 + b) * 33 + 16 + col16] = acc1[rr];
        }

        __syncthreads();

        // ---- EARLY poll issue (r13): RTT hides under pointwise + h-store +
        // store_x; polls stay OLDEST so wait_vm1 never pays the store ack.
        const uint32_t* src = hbuf32 + (size_t)(t + 1) * (BATCH * HDIM / 2)
                                     + (size_t)b0 * (HDIM / 2);
        const uint32_t* p0 = src + (size_t)prow0 * (HDIM / 2) + rc8 * 4;
        const uint32_t* p1 = src + (size_t)prow1 * (HDIM / 2) + rc8 * 4;

        if (!last && !ownm) {
            issue4_dev(v0, p0); issue4_dev(v1, p1);
        }

        // ---- pointwise (overlaps poll RTT) ----
        float pi0 = gbuf[pm][(0 * 16 + r) * 33 + c0l] + bi0;
        float pi1 = gbuf[pm][(0 * 16 + r) * 33 + c0l + 1] + bi1;
        float pf0 = gbuf[pm][(1 * 16 + r) * 33 + c0l] + bf0;
        float pf1 = gbuf[pm][(1 * 16 + r) * 33 + c0l + 1] + bf1;
        float po0 = gbuf[pm][(2 * 16 + r) * 33 + c0l] + bo0;
        float po1 = gbuf[pm][(2 * 16 + r) * 33 + c0l + 1] + bo1;
        float pc0 = gbuf[pm][(3 * 16 + r) * 33 + c0l] + bc0;
        float pc1 = gbuf[pm][(3 * 16 + r) * 33 + c0l + 1] + bc1;

        float I0 = sigm(pi0), F0 = sigm(pf0), O0 = sigm(po0), G0 = tanh_f(pc0);
        float I1 = sigm(pi1), F1 = sigm(pf1), O1 = sigm(po1), G1 = tanh_f(pc1);
        C0 = F0 * C0 + I0 * G0;
        C1 = F1 * C1 + I1 * G1;
        float h0 = O0 * tanh_f(C0);
        float h1 = O1 * tanh_f(C1);

        // fire-and-forget agent store (coherence point); YOUNGEST vmem op
        uint32_t packed = (uint32_t)f2bf(h0) | ((uint32_t)f2bf(h1) << 16);
        __hip_atomic_store(&hbuf32[(size_t)(t + 1) * (BATCH * HDIM / 2) + hslot],
                           packed, __ATOMIC_RELAXED, __HIP_MEMORY_SCOPE_AGENT);

        if (last) break;

        // own 64 columns go straight to LDS — no exchange round-trip
        *(uint32_t*)(hA + r * LDA + gcol * 2) = packed;

        // store_x AFTER the h-store (r13-proven placement)
        store_x();

        // ---- poll rounds: batched reissue of pending chunks, one RTT/round ----
        wait_vm1(v0, v1);   // 2 poll loads done; h-store stays in flight
        uint32_t s0 = ownm ? 0u : has_sent(v0);
        uint32_t s1 = ownm ? 0u : has_sent(v1);
        int round = 0;
        while (s0 | s1) {
            if (++round > 50000) break;   // never hang
            if (round >= 6) __builtin_amdgcn_s_sleep(2);
            if (s0) issue4_dev(v0, p0);
            if (s1) issue4_dev(v1, p1);
            wait_vm0(v0, v1);
            s0 = has_sent(v0); s1 = has_sent(v1);
        }
        if (!ownm) {
            *(u32x4*)(hA + prow0 * LDA + rc8 * 16) = v0;
            *(u32x4*)(hA + prow1 * LDA + rc8 * 16) = v1;
        }

        __syncthreads();
    }
}

// Readout: out[t,b,:] = h[t+1] @ Wro^T + bro.  MFMA, N padded 33->48. fp32 out.
__global__ __launch_bounds__(256, 1) void lstm_out(
    const uint16_t* __restrict__ hbuf,
    const float* __restrict__ Wro, const float* __restrict__ bro,
    float* __restrict__ out)
{
    __shared__ __align__(16) uint8_t hT[64 * LDA];   // 66.6 KB

    const int tid   = threadIdx.x;
    const int bid   = blockIdx.x;
    const int wave  = tid >> 6;
    const int lane  = tid & 63;
    const int col16 = lane & 15;
    const int quad  = lane >> 4;

    s8v bw[3][16];
    float bias[3];
#pragma unroll
    for (int nt = 0; nt < 3; ++nt) {
        int o = nt * 16 + col16;
        bias[nt] = (o < NOUT) ? bro[o] : 0.f;
#pragma unroll
        for (int kt = 0; kt < 16; ++kt) {
            if (o < NOUT) {
                bw[nt][kt] = cvt8(Wro + (size_t)o * HDIM + kt * 32 + quad * 8);
            } else {
                s8v z;
#pragma unroll
                for (int q = 0; q < 8; ++q) z[q] = 0;
                bw[nt][kt] = z;
            }
        }
    }

    const uint16_t* hsrc = hbuf + (size_t)BATCH * HDIM;  // skip t=0 slot

    for (int sub = 0; sub < 8; ++sub) {
        size_t row0 = (size_t)bid * 512 + (size_t)sub * 64;
#pragma unroll
        for (int j = 0; j < 16; ++j) {
            int v = tid + j * 256;
            int row = v >> 6, c8 = v & 63;
            s8v val = *(const s8v*)(hsrc + (row0 + row) * HDIM + c8 * 8);
            *(s8v*)(hT + row * LDA + c8 * 16) = val;
        }
        __syncthreads();

        f4v acc[3];
#pragma unroll
        for (int nt = 0; nt < 3; ++nt) acc[nt] = (f4v){0.f, 0.f, 0.f, 0.f};
#pragma unroll
        for (int kt = 0; kt < 16; ++kt) {
            s8v a = *(const s8v*)(hT + (wave * 16 + col16) * LDA + kt * 64 + quad * 16);
#pragma unroll
            for (int nt = 0; nt < 3; ++nt)
                acc[nt] = __builtin_amdgcn_mfma_f32_16x16x32_bf16(a, bw[nt][kt], acc[nt], 0, 0, 0);
        }
#pragma unroll
        for (int nt = 0; nt < 3; ++nt) {
            int o = nt * 16 + col16;
            if (o < NOUT) {
#pragma unroll
                for (int rr = 0; rr < 4; ++rr) {
                    size_t rg = row0 + (size_t)wave * 16 + quad * 4 + rr;
                    out[rg * NOUT + o] = acc[nt][rr] + bias[nt];
                }
            }
        }
        __syncthreads();
    }
}

extern "C" void kernel_launch(void* const* d_in, const int* in_sizes, int n_in,
                              void* d_out, int out_size, void* d_ws, size_t ws_size,
                              hipStream_t stream)
{
    const float* x   = (const float*)d_in[0];
    const float* Wxi = (const float*)d_in[1];
    const float* Wxf = (const float*)d_in[2];
    const float* Wxo = (const float*)d_in[3];
    const float* Wxc = (const float*)d_in[4];
    const float* Whi = (const float*)d_in[5];
    const float* bhi = (const float*)d_in[6];
    const float* Whf = (const float*)d_in[7];
    const float* bhf = (const float*)d_in[8];
    const float* Who = (const float*)d_in[9];
    const float* bho = (const float*)d_in[10];
    const float* Whc = (const float*)d_in[11];
    const float* bhc = (const float*)d_in[12];
    const float* Wro = (const float*)d_in[13];
    const float* bro = (const float*)d_in[14];
    float* out = (float*)d_out;

    uint16_t* hbuf = (uint16_t*)d_ws;   // (T+1)*B*H*2 = 134.5 MB

    lstm_init<<<2048, 256, 0, stream>>>((uint32_t*)hbuf);
    lstm_rec<<<128, 512, 0, stream>>>(x, Wxi, Wxf, Wxo, Wxc,
                                      Whi, bhi, Whf, bhf, Who, bho, Whc, bhc,
                                      hbuf);
    lstm_out<<<256, 256, 0, stream>>>(hbuf, Wro, bro, out);
}

// Round 11
// 1670.323 us; speedup vs baseline: 1.0080x; 1.0080x over previous
//
#include <hip/hip_runtime.h>
#include <hip/hip_bf16.h>
#include <stdint.h>

#define T_STEPS 512
#define BATCH   256
#define DIN     85
#define HDIM    512
#define NOUT    33

#define BBLK  16     // batch rows per group
#define HS    32     // H columns per wave-member slice
#define LDA   1040   // bytes per padded row of h A-tile (520 elems, 16B-aligned)
#define LDX   208    // bytes per padded row of x A-tile (104 elems)

// bf16 NaN|NaN pair — unreachable as packed h output (|h|<1, finite),
// used as the "not yet written" sentinel so the data is its own flag.
#define SENT  0x7FC07FC0u

typedef __attribute__((ext_vector_type(8))) short s8v;       // 8 x bf16
typedef __attribute__((ext_vector_type(4))) float f4v;       // MFMA accumulator
typedef __attribute__((ext_vector_type(4))) uint32_t u32x4;  // 16B chunk

__device__ __forceinline__ uint16_t f2bf(float f) {
    uint32_t x = __builtin_bit_cast(uint32_t, f);
    uint32_t r = (x + 0x7fffu + ((x >> 16) & 1u)) >> 16;
    return (uint16_t)r;
}
__device__ __forceinline__ float sigm(float v) {
    v = fminf(fmaxf(v, -30.f), 30.f);
    return 1.f / (1.f + __expf(-v));
}
__device__ __forceinline__ float tanh_f(float v) {
    v = fminf(fmaxf(v, -15.f), 15.f);
    float e = __expf(2.f * v);
    return (e - 1.f) / (e + 1.f);
}
__device__ __forceinline__ s8v cvt8(const float* p) {
    s8v v;
#pragma unroll
    for (int j = 0; j < 8; ++j) v[j] = (short)f2bf(p[j]);
    return v;
}

// r17 = r16 with the VGPR cap ACTUALLY lifted. r15/r16 both spilled the
// weight fragments (VGPR_Count=128 < ~215 demand -> +41MB scratch writes,
// +87MB scratch reads) because launch_bounds' 2nd arg only sets a MINIMUM
// waves/EU — the backend still targets its default occupancy and allocates
// 128. The max field of amdgpu_waves_per_eu(min,max) is the knob that forces
// 2 waves/EU -> 256-VGPR cap. With the spill gone this finally tests the
// fusion hypothesis: intra-block exchange via LDS, each block polls only
// 7/8 of the h-tile => aggregate poll volume -53% (MALL-request-rate bound
// per r14's superlinear slowdown with added probe volume).
__device__ __forceinline__ void issue4_dev(u32x4& v, const uint32_t* p) {
    asm volatile("global_load_dwordx4 %0, %1, off sc0 sc1"
                 : "+v"(v) : "v"(p) : "memory");
}
__device__ __forceinline__ void wait_vm1(u32x4& a, u32x4& b) {
    // in-order retirement (m135): <=1 outstanding means the 2 older poll
    // loads are done while the younger fire-and-forget h-store may still be
    // in flight — we never pay for the store ack.
    asm volatile("s_waitcnt vmcnt(1)"
                 : "+v"(a), "+v"(b) :: "memory");
}
__device__ __forceinline__ void wait_vm0(u32x4& a, u32x4& b) {
    asm volatile("s_waitcnt vmcnt(0)"
                 : "+v"(a), "+v"(b) :: "memory");
}
__device__ __forceinline__ uint32_t has_sent(const u32x4& v) {
    return (uint32_t)(v[0] == SENT) | (uint32_t)(v[1] == SENT) |
           (uint32_t)(v[2] == SENT) | (uint32_t)(v[3] == SENT);
}

// Fill hbuf with the sentinel before the recurrence.
__global__ __launch_bounds__(256) void lstm_init(uint32_t* __restrict__ hbuf)
{
    const size_t n4 = (size_t)(T_STEPS + 1) * BATCH * HDIM / 2 / 4;
    u32x4 s; s[0] = SENT; s[1] = SENT; s[2] = SENT; s[3] = SENT;
    u32x4* p = (u32x4*)hbuf;
    for (size_t i = (size_t)blockIdx.x * 256 + threadIdx.x; i < n4;
         i += (size_t)gridDim.x * 256)
        p[i] = s;
}

// Persistent recurrence kernel. 128 blocks x 512 threads = 16 groups x 8
// blocks; each block hosts 2 members (64 H-cols), 8 waves = 2 members x 4
// gates. Group owns 16 batch rows. Weights live in registers per wave.
// amdgpu_waves_per_eu(2,2): exactly 2 waves/EU -> 256-VGPR cap, 1 wg/CU;
// 128 blocks <= 256 CUs so protocol co-residency holds.
// Post-barrier order (r13-proven): poll issue -> pointwise -> h-store ->
// own-col LDS -> store_x -> wait_vm1 -> reissue rounds -> hA writes -> barrier.
__global__ __launch_bounds__(512)
__attribute__((amdgpu_waves_per_eu(2, 2))) void lstm_rec(
    const float* __restrict__ x,
    const float* __restrict__ Wxi, const float* __restrict__ Wxf,
    const float* __restrict__ Wxo, const float* __restrict__ Wxc,
    const float* __restrict__ Whi, const float* __restrict__ bhi,
    const float* __restrict__ Whf, const float* __restrict__ bhf,
    const float* __restrict__ Who, const float* __restrict__ bho,
    const float* __restrict__ Whc, const float* __restrict__ bhc,
    uint16_t* __restrict__ hbuf)      // [T_STEPS+1][BATCH][HDIM] bf16 (scratch)
{
    __shared__ __align__(16) uint8_t hA[16 * LDA];   // 16.6 KB
    __shared__ __align__(16) uint8_t xA[16 * LDX];   // 3.3 KB
    __shared__ float gbuf[2][4 * 16 * 33];           // 16.9 KB

    const int tid  = threadIdx.x;
    const int bid  = blockIdx.x;
    const int xcd  = bid & 7;
    const int slot = bid >> 3;            // 0..15
    const int grp  = xcd * 2 + (slot >> 3);
    const int blkm = slot & 7;            // block index within group, 0..7
    const int b0   = grp * BBLK;
    const int bslice = blkm * 64;         // block's 64 own columns

    const int wave  = tid >> 6;           // 0..7
    const int memb  = wave >> 2;          // member within block: 0..1
    const int gate  = wave & 3;           // 0=i 1=f 2=o 3=c
    const int lane  = tid & 63;
    const int col16 = lane & 15;
    const int quad  = lane >> 4;
    const int hs    = bslice + memb * HS; // this wave's 32 columns

    const float* Wh  = (gate == 0) ? Whi : (gate == 1) ? Whf : (gate == 2) ? Who : Whc;
    const float* Wxp = (gate == 0) ? Wxi : (gate == 1) ? Wxf : (gate == 2) ? Wxo : Wxc;

    // ---- B-fragments (weights) into registers, once (fp32 -> bf16 RNE) ----
    s8v bh[2][16];
#pragma unroll
    for (int nt = 0; nt < 2; ++nt) {
        const float* rowp = Wh + (size_t)(hs + nt * 16 + col16) * HDIM;
#pragma unroll
        for (int kt = 0; kt < 16; ++kt)
            bh[nt][kt] = cvt8(rowp + kt * 32 + quad * 8);
    }
    s8v bx[2][3];
#pragma unroll
    for (int nt = 0; nt < 2; ++nt) {
        const float* rowp = Wxp + (size_t)(hs + nt * 16 + col16) * DIN;
#pragma unroll
        for (int kt = 0; kt < 3; ++kt) {
            s8v v;
#pragma unroll
            for (int j = 0; j < 8; ++j) {
                int k = kt * 32 + quad * 8 + j;
                v[j] = (k < DIN) ? (short)f2bf(rowp[k]) : (short)0;
            }
            bx[nt][kt] = v;
        }
    }

    // ---- pointwise mapping: thread -> (member pm, row r, cols gcol,gcol+1) ----
    const int pm   = tid >> 8;                 // member whose slice we finish
    const int t256 = tid & 255;
    const int r    = t256 >> 4;
    const int c0l  = (t256 & 15) * 2;          // col within member's 32
    const int gcol = bslice + pm * HS + c0l;   // global H column
    const float bi0 = bhi[gcol], bi1 = bhi[gcol + 1];
    const float bf0 = bhf[gcol], bf1 = bhf[gcol + 1];
    const float bo0 = bho[gcol], bo1 = bho[gcol + 1];
    const float bc0 = bhc[gcol], bc1 = bhc[gcol + 1];
    float C0 = 0.f, C1 = 0.f;

    uint32_t* hbuf32 = (uint32_t*)hbuf;
    const size_t hslot = ((size_t)(b0 + r) * HDIM + gcol) >> 1;

    // ---- poll chunk mapping: 1024 chunks (16 rows x 64 16B-cols), 2/thread
    const int prow0 = tid >> 6;          // rows 0..7
    const int prow1 = prow0 + 8;         // rows 8..15
    const int rc8   = tid & 63;          // 16B column
    // block's own 64 cols = 8 chunk-cols [blkm*8, blkm*8+8): arrive via LDS
    const uint32_t ownm = ((uint32_t)(rc8 >> 3) == (uint32_t)blkm) ? 1u : 0u;

    // ---- x prefetch (fp32 registers): 1536 slots = 512 threads x 3 ----
    float xreg[3];
    auto load_x = [&](int t) {
#pragma unroll
        for (int j = 0; j < 3; ++j) {
            int v = tid + j * 512;
            int row = v / 96, k = v % 96;
            xreg[j] = (k < DIN) ? x[(size_t)(t * BATCH + b0 + row) * DIN + k] : 0.f;
        }
    };
    auto store_x = [&]() {
#pragma unroll
        for (int j = 0; j < 3; ++j) {
            int v = tid + j * 512;
            int row = v / 96, k = v % 96;
            *(uint16_t*)(xA + row * LDX + k * 2) = f2bf(xreg[j]);
        }
    };

    // init: h(0)=0 in LDS, stage x(0)
    load_x(0);
    for (int j = tid; j < 16 * LDA / 16; j += 512) {
        s8v z;
#pragma unroll
        for (int q = 0; q < 8; ++q) z[q] = 0;
        ((s8v*)hA)[j] = z;
    }
    store_x();
    __syncthreads();

    u32x4 v0 = {SENT, SENT, SENT, SENT};
    u32x4 v1 = v0;

    for (int t = 0; t < T_STEPS; ++t) {
        const int last = (t == T_STEPS - 1);

        // x(t+1) loads fly under the GEMM
        if (!last) load_x(t + 1);

        // ---- GEMM: this wave's gate, 16 rows x 32 cols (identical to r13) ----
        f4v acc0 = {0.f, 0.f, 0.f, 0.f}, acc1 = {0.f, 0.f, 0.f, 0.f};
#pragma unroll
        for (int kt = 0; kt < 16; ++kt) {
            s8v a = *(const s8v*)(hA + col16 * LDA + kt * 64 + quad * 16);
            acc0 = __builtin_amdgcn_mfma_f32_16x16x32_bf16(a, bh[0][kt], acc0, 0, 0, 0);
            acc1 = __builtin_amdgcn_mfma_f32_16x16x32_bf16(a, bh[1][kt], acc1, 0, 0, 0);
        }
#pragma unroll
        for (int kt = 0; kt < 3; ++kt) {
            s8v a = *(const s8v*)(xA + col16 * LDX + kt * 64 + quad * 16);
            acc0 = __builtin_amdgcn_mfma_f32_16x16x32_bf16(a, bx[0][kt], acc0, 0, 0, 0);
            acc1 = __builtin_amdgcn_mfma_f32_16x16x32_bf16(a, bx[1][kt], acc1, 0, 0, 0);
        }
        // Raw pre-activations to the member's gbuf. C/D: col=lane&15, row=quad*4+rr
#pragma unroll
        for (int rr = 0; rr < 4; ++rr) {
            int b = quad * 4 + rr;
            gbuf[memb][(gate * 16 + b) * 33 + col16]      = acc0[rr];
            gbuf[memb][(gate * 16 + b) * 33 + 16 + col16] = acc1[rr];
        }

        __syncthreads();

        // ---- EARLY poll issue (r13): RTT hides under pointwise + h-store +
        // store_x; polls stay OLDEST so wait_vm1 never pays the store ack.
        const uint32_t* src = hbuf32 + (size_t)(t + 1) * (BATCH * HDIM / 2)
                                     + (size_t)b0 * (HDIM / 2);
        const uint32_t* p0 = src + (size_t)prow0 * (HDIM / 2) + rc8 * 4;
        const uint32_t* p1 = src + (size_t)prow1 * (HDIM / 2) + rc8 * 4;

        if (!last && !ownm) {
            issue4_dev(v0, p0); issue4_dev(v1, p1);
        }

        // ---- pointwise (overlaps poll RTT) ----
        float pi0 = gbuf[pm][(0 * 16 + r) * 33 + c0l] + bi0;
        float pi1 = gbuf[pm][(0 * 16 + r) * 33 + c0l + 1] + bi1;
        float pf0 = gbuf[pm][(1 * 16 + r) * 33 + c0l] + bf0;
        float pf1 = gbuf[pm][(1 * 16 + r) * 33 + c0l + 1] + bf1;
        float po0 = gbuf[pm][(2 * 16 + r) * 33 + c0l] + bo0;
        float po1 = gbuf[pm][(2 * 16 + r) * 33 + c0l + 1] + bo1;
        float pc0 = gbuf[pm][(3 * 16 + r) * 33 + c0l] + bc0;
        float pc1 = gbuf[pm][(3 * 16 + r) * 33 + c0l + 1] + bc1;

        float I0 = sigm(pi0), F0 = sigm(pf0), O0 = sigm(po0), G0 = tanh_f(pc0);
        float I1 = sigm(pi1), F1 = sigm(pf1), O1 = sigm(po1), G1 = tanh_f(pc1);
        C0 = F0 * C0 + I0 * G0;
        C1 = F1 * C1 + I1 * G1;
        float h0 = O0 * tanh_f(C0);
        float h1 = O1 * tanh_f(C1);

        // fire-and-forget agent store (coherence point); YOUNGEST vmem op
        uint32_t packed = (uint32_t)f2bf(h0) | ((uint32_t)f2bf(h1) << 16);
        __hip_atomic_store(&hbuf32[(size_t)(t + 1) * (BATCH * HDIM / 2) + hslot],
                           packed, __ATOMIC_RELAXED, __HIP_MEMORY_SCOPE_AGENT);

        if (last) break;

        // own 64 columns go straight to LDS — no exchange round-trip
        *(uint32_t*)(hA + r * LDA + gcol * 2) = packed;

        // store_x AFTER the h-store (r13-proven placement)
        store_x();

        // ---- poll rounds: batched reissue of pending chunks, one RTT/round ----
        wait_vm1(v0, v1);   // 2 poll loads done; h-store stays in flight
        uint32_t s0 = ownm ? 0u : has_sent(v0);
        uint32_t s1 = ownm ? 0u : has_sent(v1);
        int round = 0;
        while (s0 | s1) {
            if (++round > 50000) break;   // never hang
            if (round >= 6) __builtin_amdgcn_s_sleep(2);
            if (s0) issue4_dev(v0, p0);
            if (s1) issue4_dev(v1, p1);
            wait_vm0(v0, v1);
            s0 = has_sent(v0); s1 = has_sent(v1);
        }
        if (!ownm) {
            *(u32x4*)(hA + prow0 * LDA + rc8 * 16) = v0;
            *(u32x4*)(hA + prow1 * LDA + rc8 * 16) = v1;
        }

        __syncthreads();
    }
}

// Readout: out[t,b,:] = h[t+1] @ Wro^T + bro.  MFMA, N padded 33->48. fp32 out.
__global__ __launch_bounds__(256, 1) void lstm_out(
    const uint16_t* __restrict__ hbuf,
    const float* __restrict__ Wro, const float* __restrict__ bro,
    float* __restrict__ out)
{
    __shared__ __align__(16) uint8_t hT[64 * LDA];   // 66.6 KB

    const int tid   = threadIdx.x;
    const int bid   = blockIdx.x;
    const int wave  = tid >> 6;
    const int lane  = tid & 63;
    const int col16 = lane & 15;
    const int quad  = lane >> 4;

    s8v bw[3][16];
    float bias[3];
#pragma unroll
    for (int nt = 0; nt < 3; ++nt) {
        int o = nt * 16 + col16;
        bias[nt] = (o < NOUT) ? bro[o] : 0.f;
#pragma unroll
        for (int kt = 0; kt < 16; ++kt) {
            if (o < NOUT) {
                bw[nt][kt] = cvt8(Wro + (size_t)o * HDIM + kt * 32 + quad * 8);
            } else {
                s8v z;
#pragma unroll
                for (int q = 0; q < 8; ++q) z[q] = 0;
                bw[nt][kt] = z;
            }
        }
    }

    const uint16_t* hsrc = hbuf + (size_t)BATCH * HDIM;  // skip t=0 slot

    for (int sub = 0; sub < 8; ++sub) {
        size_t row0 = (size_t)bid * 512 + (size_t)sub * 64;
#pragma unroll
        for (int j = 0; j < 16; ++j) {
            int v = tid + j * 256;
            int row = v >> 6, c8 = v & 63;
            s8v val = *(const s8v*)(hsrc + (row0 + row) * HDIM + c8 * 8);
            *(s8v*)(hT + row * LDA + c8 * 16) = val;
        }
        __syncthreads();

        f4v acc[3];
#pragma unroll
        for (int nt = 0; nt < 3; ++nt) acc[nt] = (f4v){0.f, 0.f, 0.f, 0.f};
#pragma unroll
        for (int kt = 0; kt < 16; ++kt) {
            s8v a = *(const s8v*)(hT + (wave * 16 + col16) * LDA + kt * 64 + quad * 16);
#pragma unroll
            for (int nt = 0; nt < 3; ++nt)
                acc[nt] = __builtin_amdgcn_mfma_f32_16x16x32_bf16(a, bw[nt][kt], acc[nt], 0, 0, 0);
        }
#pragma unroll
        for (int nt = 0; nt < 3; ++nt) {
            int o = nt * 16 + col16;
            if (o < NOUT) {
#pragma unroll
                for (int rr = 0; rr < 4; ++rr) {
                    size_t rg = row0 + (size_t)wave * 16 + quad * 4 + rr;
                    out[rg * NOUT + o] = acc[nt][rr] + bias[nt];
                }
            }
        }
        __syncthreads();
    }
}

extern "C" void kernel_launch(void* const* d_in, const int* in_sizes, int n_in,
                              void* d_out, int out_size, void* d_ws, size_t ws_size,
                              hipStream_t stream)
{
    const float* x   = (const float*)d_in[0];
    const float* Wxi = (const float*)d_in[1];
    const float* Wxf = (const float*)d_in[2];
    const float* Wxo = (const float*)d_in[3];
    const float* Wxc = (const float*)d_in[4];
    const float* Whi = (const float*)d_in[5];
    const float* bhi = (const float*)d_in[6];
    const float* Whf = (const float*)d_in[7];
    const float* bhf = (const float*)d_in[8];
    const float* Who = (const float*)d_in[9];
    const float* bho = (const float*)d_in[10];
    const float* Whc = (const float*)d_in[11];
    const float* bhc = (const float*)d_in[12];
    const float* Wro = (const float*)d_in[13];
    const float* bro = (const float*)d_in[14];
    float* out = (float*)d_out;

    uint16_t* hbuf = (uint16_t*)d_ws;   // (T+1)*B*H*2 = 134.5 MB

    lstm_init<<<2048, 256, 0, stream>>>((uint32_t*)hbuf);
    lstm_rec<<<128, 512, 0, stream>>>(x, Wxi, Wxf, Wxo, Wxc,
                                      Whi, bhi, Whf, bhf, Who, bho, Whc, bhc,
                                      hbuf);
    lstm_out<<<256, 256, 0, stream>>>(hbuf, Wro, bro, out);
}

// Round 12
// 1250.340 us; speedup vs baseline: 1.3465x; 1.3359x over previous
//
#include <hip/hip_runtime.h>
#include <hip/hip_bf16.h>
#include <stdint.h>

#define T_STEPS 512
#define BATCH   256
#define DIN     85
#define HDIM    512
#define NOUT    33

#define BBLK  16     // batch rows per group
#define HS    32     // H columns per block
#define LDA   1040   // bytes per padded row of h A-tile (520 elems, 16B-aligned)
#define LDX   208    // bytes per padded row of x A-tile (104 elems)

// bf16 NaN|NaN pair — unreachable as packed h output (|h|<1, finite),
// used as the "not yet written" sentinel so the data is its own flag.
#define SENT  0x7FC07FC0u

typedef __attribute__((ext_vector_type(8))) short s8v;       // 8 x bf16
typedef __attribute__((ext_vector_type(4))) float f4v;       // MFMA accumulator
typedef __attribute__((ext_vector_type(4))) uint32_t u32x4;  // 16B chunk

__device__ __forceinline__ uint16_t f2bf(float f) {
    uint32_t x = __builtin_bit_cast(uint32_t, f);
    uint32_t r = (x + 0x7fffu + ((x >> 16) & 1u)) >> 16;
    return (uint16_t)r;
}
__device__ __forceinline__ float sigm(float v) {
    v = fminf(fmaxf(v, -30.f), 30.f);
    return 1.f / (1.f + __expf(-v));
}
__device__ __forceinline__ float tanh_f(float v) {
    v = fminf(fmaxf(v, -15.f), 15.f);
    float e = __expf(2.f * v);
    return (e - 1.f) / (e + 1.f);
}
__device__ __forceinline__ s8v cvt8(const float* p) {
    s8v v;
#pragma unroll
    for (int j = 0; j < 8; ++j) v[j] = (short)f2bf(p[j]);
    return v;
}

// r18 = exact revert to r13 (best measured: 1152us lstm_rec, no spill).
// Closed avenues (measured): late poll issue (r11 −), producer-side
// activation (r12 −), double-probe (r14 −, MALL request-rate bound),
// sc0-only XCD-L2 exchange (r10 incorrect on HW), 512-thread fusion
// (r15/r16/r17: VGPR allocator caps 8-wave blocks at 128 -> weight spill;
// launch_bounds min-waves and amdgpu_waves_per_eu(2,2) both failed to lift).
__device__ __forceinline__ void issue4_dev(u32x4& v, const uint32_t* p) {
    asm volatile("global_load_dwordx4 %0, %1, off sc0 sc1"
                 : "+v"(v) : "v"(p) : "memory");
}
__device__ __forceinline__ void wait_vm1(u32x4& a, u32x4& b, u32x4& c, u32x4& d) {
    // vmcnt retires oldest-first (m135): <=1 outstanding means the 4 older
    // poll loads are done while the younger fire-and-forget h-store may still
    // be in flight — we never pay for the store ack.
    asm volatile("s_waitcnt vmcnt(1)"
                 : "+v"(a), "+v"(b), "+v"(c), "+v"(d) :: "memory");
}
__device__ __forceinline__ void wait_vm0(u32x4& a, u32x4& b, u32x4& c, u32x4& d) {
    asm volatile("s_waitcnt vmcnt(0)"
                 : "+v"(a), "+v"(b), "+v"(c), "+v"(d) :: "memory");
}
__device__ __forceinline__ uint32_t has_sent(const u32x4& v) {
    return (uint32_t)(v[0] == SENT) | (uint32_t)(v[1] == SENT) |
           (uint32_t)(v[2] == SENT) | (uint32_t)(v[3] == SENT);
}

// Fill hbuf with the sentinel before the recurrence.
__global__ __launch_bounds__(256) void lstm_init(uint32_t* __restrict__ hbuf)
{
    const size_t n4 = (size_t)(T_STEPS + 1) * BATCH * HDIM / 2 / 4;
    u32x4 s; s[0] = SENT; s[1] = SENT; s[2] = SENT; s[3] = SENT;
    u32x4* p = (u32x4*)hbuf;
    for (size_t i = (size_t)blockIdx.x * 256 + threadIdx.x; i < n4;
         i += (size_t)gridDim.x * 256)
        p[i] = s;
}

// Persistent recurrence kernel. 256 blocks = 16 groups x 16 members.
// Group owns 16 batch rows; member owns 32 H columns (x4 gates, one per wave).
// Weights live in registers as MFMA B-fragments for the whole kernel.
// Post-barrier order (r13-proven): poll issue -> pointwise -> h-store ->
// own-col LDS -> store_x -> wait_vm1 -> reissue rounds -> hA writes -> barrier.
__global__ __launch_bounds__(256, 1) void lstm_rec(
    const float* __restrict__ x,
    const float* __restrict__ Wxi, const float* __restrict__ Wxf,
    const float* __restrict__ Wxo, const float* __restrict__ Wxc,
    const float* __restrict__ Whi, const float* __restrict__ bhi,
    const float* __restrict__ Whf, const float* __restrict__ bhf,
    const float* __restrict__ Who, const float* __restrict__ bho,
    const float* __restrict__ Whc, const float* __restrict__ bhc,
    uint16_t* __restrict__ hbuf)      // [T_STEPS+1][BATCH][HDIM] bf16 (scratch)
{
    __shared__ __align__(16) uint8_t hA[16 * LDA];   // 16.6 KB
    __shared__ __align__(16) uint8_t xA[16 * LDX];   // 3.3 KB
    __shared__ float gbuf[4 * 16 * 33];              // 8.4 KB

    const int tid  = threadIdx.x;
    const int bid  = blockIdx.x;
    const int xcd  = bid & 7;
    const int slot = bid >> 3;
    const int grp  = xcd * 2 + (slot >> 4);
    const int mem  = slot & 15;
    const int b0   = grp * BBLK;
    const int hs   = mem * HS;

    const int wave  = tid >> 6;       // gate: 0=i 1=f 2=o 3=c
    const int lane  = tid & 63;
    const int col16 = lane & 15;
    const int quad  = lane >> 4;

    const float* Wh  = (wave == 0) ? Whi : (wave == 1) ? Whf : (wave == 2) ? Who : Whc;
    const float* Wxp = (wave == 0) ? Wxi : (wave == 1) ? Wxf : (wave == 2) ? Wxo : Wxc;

    // ---- B-fragments (weights) into registers, once (fp32 -> bf16 RNE) ----
    s8v bh[2][16];
#pragma unroll
    for (int nt = 0; nt < 2; ++nt) {
        const float* rowp = Wh + (size_t)(hs + nt * 16 + col16) * HDIM;
#pragma unroll
        for (int kt = 0; kt < 16; ++kt)
            bh[nt][kt] = cvt8(rowp + kt * 32 + quad * 8);
    }
    s8v bx[2][3];
#pragma unroll
    for (int nt = 0; nt < 2; ++nt) {
        const float* rowp = Wxp + (size_t)(hs + nt * 16 + col16) * DIN;
#pragma unroll
        for (int kt = 0; kt < 3; ++kt) {
            s8v v;
#pragma unroll
            for (int j = 0; j < 8; ++j) {
                int k = kt * 32 + quad * 8 + j;
                v[j] = (k < DIN) ? (short)f2bf(rowp[k]) : (short)0;
            }
            bx[nt][kt] = v;
        }
    }

    // ---- pointwise mapping: thread -> (row r, cols c0,c0+1) of 16x32 slice ----
    const int r  = tid >> 4;
    const int c0 = (tid & 15) * 2;
    const float bi0 = bhi[hs + c0], bi1 = bhi[hs + c0 + 1];
    const float bf0 = bhf[hs + c0], bf1 = bhf[hs + c0 + 1];
    const float bo0 = bho[hs + c0], bo1 = bho[hs + c0 + 1];
    const float bc0 = bhc[hs + c0], bc1 = bhc[hs + c0 + 1];
    float C0 = 0.f, C1 = 0.f;

    uint32_t* hbuf32 = (uint32_t*)hbuf;
    const size_t hslot = ((size_t)(b0 + r) * HDIM + hs + c0) >> 1;

    // ---- refill chunk mapping: chunk c = tid + 256q -> row c>>6, 16B col c&63
    const int rrow[4] = { tid >> 6, (tid + 256) >> 6, (tid + 512) >> 6, (tid + 768) >> 6 };
    const int rc8     = tid & 63;
    // own 32 columns = 4 chunk-cols; they arrive via LDS, never via poll
    const uint32_t ownm = (rc8 >= mem * 4 && rc8 < mem * 4 + 4) ? 1u : 0u;

    // ---- x prefetch (fp32 registers) ----
    float xreg[6];
    auto load_x = [&](int t) {
#pragma unroll
        for (int j = 0; j < 6; ++j) {
            int v = tid + j * 256;
            int row = v / 96, k = v % 96;
            xreg[j] = (k < DIN) ? x[(size_t)(t * BATCH + b0 + row) * DIN + k] : 0.f;
        }
    };
    auto store_x = [&]() {
#pragma unroll
        for (int j = 0; j < 6; ++j) {
            int v = tid + j * 256;
            int row = v / 96, k = v % 96;
            *(uint16_t*)(xA + row * LDX + k * 2) = f2bf(xreg[j]);
        }
    };

    // init: h(0)=0 in LDS, stage x(0)
    load_x(0);
    for (int j = tid; j < 16 * LDA / 16; j += 256) {
        s8v z;
#pragma unroll
        for (int q = 0; q < 8; ++q) z[q] = 0;
        ((s8v*)hA)[j] = z;
    }
    store_x();
    __syncthreads();

    u32x4 v0 = {SENT, SENT, SENT, SENT};
    u32x4 v1 = v0, v2 = v0, v3 = v0;

    for (int t = 0; t < T_STEPS; ++t) {
        const int last = (t == T_STEPS - 1);

        // x(t+1) loads fly under the GEMM (done well before store_x needs them)
        if (!last) load_x(t + 1);

        // ---- GEMM: pre-activations for this wave's gate, 16 rows x 32 cols ----
        f4v acc0 = {0.f, 0.f, 0.f, 0.f}, acc1 = {0.f, 0.f, 0.f, 0.f};
#pragma unroll
        for (int kt = 0; kt < 16; ++kt) {
            s8v a = *(const s8v*)(hA + col16 * LDA + kt * 64 + quad * 16);
            acc0 = __builtin_amdgcn_mfma_f32_16x16x32_bf16(a, bh[0][kt], acc0, 0, 0, 0);
            acc1 = __builtin_amdgcn_mfma_f32_16x16x32_bf16(a, bh[1][kt], acc1, 0, 0, 0);
        }
#pragma unroll
        for (int kt = 0; kt < 3; ++kt) {
            s8v a = *(const s8v*)(xA + col16 * LDX + kt * 64 + quad * 16);
            acc0 = __builtin_amdgcn_mfma_f32_16x16x32_bf16(a, bx[0][kt], acc0, 0, 0, 0);
            acc1 = __builtin_amdgcn_mfma_f32_16x16x32_bf16(a, bx[1][kt], acc1, 0, 0, 0);
        }
        // Raw pre-activations to LDS. C/D: col=lane&15, row=quad*4+rr
#pragma unroll
        for (int rr = 0; rr < 4; ++rr) {
            int b = quad * 4 + rr;
            gbuf[(wave * 16 + b) * 33 + col16]      = acc0[rr];
            gbuf[(wave * 16 + b) * 33 + 16 + col16] = acc1[rr];
        }

        __syncthreads();

        // ---- EARLY poll issue: round-1 RTT hides under pointwise + h-store
        // + store_x; polls stay OLDER than the h-store so wait_vm1 never pays
        // the store ack.
        const uint32_t* src = hbuf32 + (size_t)(t + 1) * (BATCH * HDIM / 2)
                                     + (size_t)b0 * (HDIM / 2);
        const uint32_t* p0 = src + (size_t)rrow[0] * (HDIM / 2) + rc8 * 4;
        const uint32_t* p1 = src + (size_t)rrow[1] * (HDIM / 2) + rc8 * 4;
        const uint32_t* p2 = src + (size_t)rrow[2] * (HDIM / 2) + rc8 * 4;
        const uint32_t* p3 = src + (size_t)rrow[3] * (HDIM / 2) + rc8 * 4;

        if (!last && !ownm) {
            issue4_dev(v0, p0); issue4_dev(v1, p1);
            issue4_dev(v2, p2); issue4_dev(v3, p3);
        }

        // ---- pointwise (full, consumer-side — overlaps poll RTT) ----
        float pi0 = gbuf[(0 * 16 + r) * 33 + c0] + bi0;
        float pi1 = gbuf[(0 * 16 + r) * 33 + c0 + 1] + bi1;
        float pf0 = gbuf[(1 * 16 + r) * 33 + c0] + bf0;
        float pf1 = gbuf[(1 * 16 + r) * 33 + c0 + 1] + bf1;
        float po0 = gbuf[(2 * 16 + r) * 33 + c0] + bo0;
        float po1 = gbuf[(2 * 16 + r) * 33 + c0 + 1] + bo1;
        float pc0 = gbuf[(3 * 16 + r) * 33 + c0] + bc0;
        float pc1 = gbuf[(3 * 16 + r) * 33 + c0 + 1] + bc1;

        float I0 = sigm(pi0), F0 = sigm(pf0), O0 = sigm(po0), G0 = tanh_f(pc0);
        float I1 = sigm(pi1), F1 = sigm(pf1), O1 = sigm(po1), G1 = tanh_f(pc1);
        C0 = F0 * C0 + I0 * G0;
        C1 = F1 * C1 + I1 * G1;
        float h0 = O0 * tanh_f(C0);
        float h1 = O1 * tanh_f(C1);

        // fire-and-forget agent store (coherence point); no fence, no drain;
        // YOUNGEST vmem op -> excluded from wait_vm1
        uint32_t packed = (uint32_t)f2bf(h0) | ((uint32_t)f2bf(h1) << 16);
        __hip_atomic_store(&hbuf32[(size_t)(t + 1) * (BATCH * HDIM / 2) + hslot],
                           packed, __ATOMIC_RELAXED, __HIP_MEMORY_SCOPE_AGENT);

        if (last) break;

        // own columns go straight to LDS — no exchange round-trip for them
        *(uint32_t*)(hA + r * LDA + (hs + c0) * 2) = packed;

        // store_x AFTER the h-store (r13 reorder): the ~100cy of f2bf+LDS
        // writes now hide poll RTT instead of delaying the h-store. The
        // compiler's waitcnt here covers only the OLDER x-loads.
        store_x();

        // ---- poll rounds: batched reissue of pending chunks, one RTT/round ----
        wait_vm1(v0, v1, v2, v3);   // 4 poll loads done; h-store stays in flight
        uint32_t s0 = ownm ? 0u : has_sent(v0);
        uint32_t s1 = ownm ? 0u : has_sent(v1);
        uint32_t s2 = ownm ? 0u : has_sent(v2);
        uint32_t s3 = ownm ? 0u : has_sent(v3);
        int round = 0;
        while (s0 | s1 | s2 | s3) {
            if (++round > 50000) break;   // never hang
            if (round >= 6) __builtin_amdgcn_s_sleep(2);
            if (s0) issue4_dev(v0, p0);
            if (s1) issue4_dev(v1, p1);
            if (s2) issue4_dev(v2, p2);
            if (s3) issue4_dev(v3, p3);
            wait_vm0(v0, v1, v2, v3);
            s0 = has_sent(v0); s1 = has_sent(v1);
            s2 = has_sent(v2); s3 = has_sent(v3);
        }
        if (!ownm) {
            *(u32x4*)(hA + rrow[0] * LDA + rc8 * 16) = v0;
            *(u32x4*)(hA + rrow[1] * LDA + rc8 * 16) = v1;
            *(u32x4*)(hA + rrow[2] * LDA + rc8 * 16) = v2;
            *(u32x4*)(hA + rrow[3] * LDA + rc8 * 16) = v3;
        }

        __syncthreads();
    }
}

// Readout: out[t,b,:] = h[t+1] @ Wro^T + bro.  MFMA, N padded 33->48. fp32 out.
__global__ __launch_bounds__(256, 1) void lstm_out(
    const uint16_t* __restrict__ hbuf,
    const float* __restrict__ Wro, const float* __restrict__ bro,
    float* __restrict__ out)
{
    __shared__ __align__(16) uint8_t hT[64 * LDA];   // 66.6 KB

    const int tid   = threadIdx.x;
    const int bid   = blockIdx.x;
    const int wave  = tid >> 6;
    const int lane  = tid & 63;
    const int col16 = lane & 15;
    const int quad  = lane >> 4;

    s8v bw[3][16];
    float bias[3];
#pragma unroll
    for (int nt = 0; nt < 3; ++nt) {
        int o = nt * 16 + col16;
        bias[nt] = (o < NOUT) ? bro[o] : 0.f;
#pragma unroll
        for (int kt = 0; kt < 16; ++kt) {
            if (o < NOUT) {
                bw[nt][kt] = cvt8(Wro + (size_t)o * HDIM + kt * 32 + quad * 8);
            } else {
                s8v z;
#pragma unroll
                for (int q = 0; q < 8; ++q) z[q] = 0;
                bw[nt][kt] = z;
            }
        }
    }

    const uint16_t* hsrc = hbuf + (size_t)BATCH * HDIM;  // skip t=0 slot

    for (int sub = 0; sub < 8; ++sub) {
        size_t row0 = (size_t)bid * 512 + (size_t)sub * 64;
#pragma unroll
        for (int j = 0; j < 16; ++j) {
            int v = tid + j * 256;
            int row = v >> 6, c8 = v & 63;
            s8v val = *(const s8v*)(hsrc + (row0 + row) * HDIM + c8 * 8);
            *(s8v*)(hT + row * LDA + c8 * 16) = val;
        }
        __syncthreads();

        f4v acc[3];
#pragma unroll
        for (int nt = 0; nt < 3; ++nt) acc[nt] = (f4v){0.f, 0.f, 0.f, 0.f};
#pragma unroll
        for (int kt = 0; kt < 16; ++kt) {
            s8v a = *(const s8v*)(hT + (wave * 16 + col16) * LDA + kt * 64 + quad * 16);
#pragma unroll
            for (int nt = 0; nt < 3; ++nt)
                acc[nt] = __builtin_amdgcn_mfma_f32_16x16x32_bf16(a, bw[nt][kt], acc[nt], 0, 0, 0);
        }
#pragma unroll
        for (int nt = 0; nt < 3; ++nt) {
            int o = nt * 16 + col16;
            if (o < NOUT) {
#pragma unroll
                for (int rr = 0; rr < 4; ++rr) {
                    size_t rg = row0 + (size_t)wave * 16 + quad * 4 + rr;
                    out[rg * NOUT + o] = acc[nt][rr] + bias[nt];
                }
            }
        }
        __syncthreads();
    }
}

extern "C" void kernel_launch(void* const* d_in, const int* in_sizes, int n_in,
                              void* d_out, int out_size, void* d_ws, size_t ws_size,
                              hipStream_t stream)
{
    const float* x   = (const float*)d_in[0];
    const float* Wxi = (const float*)d_in[1];
    const float* Wxf = (const float*)d_in[2];
    const float* Wxo = (const float*)d_in[3];
    const float* Wxc = (const float*)d_in[4];
    const float* Whi = (const float*)d_in[5];
    const float* bhi = (const float*)d_in[6];
    const float* Whf = (const float*)d_in[7];
    const float* bhf = (const float*)d_in[8];
    const float* Who = (const float*)d_in[9];
    const float* bho = (const float*)d_in[10];
    const float* Whc = (const float*)d_in[11];
    const float* bhc = (const float*)d_in[12];
    const float* Wro = (const float*)d_in[13];
    const float* bro = (const float*)d_in[14];
    float* out = (float*)d_out;

    uint16_t* hbuf = (uint16_t*)d_ws;   // (T+1)*B*H*2 = 134.5 MB

    lstm_init<<<2048, 256, 0, stream>>>((uint32_t*)hbuf);
    lstm_rec<<<256, 256, 0, stream>>>(x, Wxi, Wxf, Wxo, Wxc,
                                      Whi, bhi, Whf, bhf, Who, bho, Whc, bhc,
                                      hbuf);
    lstm_out<<<256, 256, 0, stream>>>(hbuf, Wro, bro, out);
}